// Round 14
// baseline (126.900 us; speedup 1.0000x reference)
//
#include <hip/hip_runtime.h>
#include <math.h>

#define C_ 512
#define HW_ 16384
#define K_ 19
#define M_ 5
#define P_ 95
#define P2 96
#define TILES_ 4
#define GRID_ 512
#define HL2PI 470.49652900081467f  // 0.5 * 512 * ln(2*pi)

typedef __attribute__((ext_vector_type(8))) short short8;
typedef __attribute__((ext_vector_type(4))) int int4v;
typedef __attribute__((ext_vector_type(4))) float float4v;

static __device__ __forceinline__ short f2bf(float f) {
  unsigned u = __builtin_bit_cast(unsigned, f);
  unsigned r = (u + 0x7fffu + ((u >> 16) & 1u)) >> 16;
  return (short)r;
}
static __device__ __forceinline__ float bf2f(short s) {
  return __builtin_bit_cast(float, ((unsigned)(unsigned short)s) << 16);
}
static __device__ __forceinline__ int pk2(float a, float b) {
  int r;
  asm("v_cvt_pk_bf16_f32 %0, %1, %2" : "=v"(r) : "v"(a), "v"(b));
  return r;
}
static __device__ __forceinline__ short8 sq8(short8 a) {
  int4v ai = __builtin_bit_cast(int4v, a);
  int4v ri;
#pragma unroll
  for (int j = 0; j < 4; j++) {
    unsigned u = (unsigned)ai[j];
    float lo = __builtin_bit_cast(float, u << 16);
    float hi = __builtin_bit_cast(float, u & 0xffff0000u);
    ri[j] = pk2(lo * lo, hi * hi);
  }
  return __builtin_bit_cast(short8, ri);
}

__device__ __forceinline__ float block_reduce_sum(float v, volatile float* red) {
#pragma unroll
  for (int o = 32; o; o >>= 1) v += __shfl_down(v, o);
  const int lane = threadIdx.x & 63, wv = threadIdx.x >> 6;
  if (lane == 0) red[wv] = v;
  __syncthreads();
  float r = red[0] + red[1] + red[2] + red[3];
  __syncthreads();
  return r;
}

// wbf[p][k] bf16 [96][1024]: k<512: inv_var; k>=512: mu*inv_var.
// cterm[p] = -0.5*q3 - logdet - HL2PI
__global__ __launch_bounds__(256) void prep_kernel(
    const float* __restrict__ means, const float* __restrict__ diag,
    short* __restrict__ wbf, float* __restrict__ cterm) {
  const int p = blockIdx.x;
  const int tid = threadIdx.x;
  __shared__ float red[4];
  if (p >= P_) {
    for (int c = tid; c < C_; c += 256) {
      wbf[p * 1024 + c] = 0;
      wbf[p * 1024 + 512 + c] = 0;
    }
    if (tid == 0) cterm[p] = 0.f;
    return;
  }
  const float* mrow = means + (size_t)p * C_;
  const float* srow = diag + (size_t)p * C_;
  float m0 = mrow[tid], m1 = mrow[tid + 256];
  float ss = block_reduce_sum(m0 * m0 + m1 * m1, red);
  float rden = 1.f / fmaxf(sqrtf(ss), 1e-12f);
  float q3 = 0.f, ld = 0.f;
#pragma unroll
  for (int t = 0; t < 2; t++) {
    int c = tid + t * 256;
    float m = mrow[c], s = srow[c];
    float mu = m * rden;
    float iv = 1.f / (s * s);
    wbf[p * 1024 + c] = f2bf(iv);
    wbf[p * 1024 + 512 + c] = f2bf(mu * iv);
    q3 += mu * mu * iv;
    ld += logf(s);
  }
  q3 = block_reduce_sum(q3, red);
  ld = block_reduce_sum(ld, red);
  if (tid == 0) cterm[p] = -0.5f * q3 - ld - HL2PI;
}

// Producer/consumer persistent block: 512 threads = 4 consumer + 4 producer
// waves; 512 blocks x 4 tiles of 32 px. Ring of 3 x 16KB half-tile buffers
// (bf16 x-frags, R12 layout at half granularity: blk=(q>>2)*8+(cgr>>2),
// slot=((cgr&1)*4+r)*8+(q&3)*2+((cgr>>1)&1)). Pipeline: (t,h) produced at
// phase 2t+h into slot ph%3, consumed at ph+2 from slot (ph+1)%3.
// Consumers: stats-finalize -> RMW x->v in LDS -> MFMA half (acc over halves;
// each wave owns (phalf,pxt) and computes BOTH q1 (sq8) and q2) -> at h1:
// rn, in-register logp -> lp -> max/LN-K/store (all 512 threads help).
__global__ __launch_bounds__(512, 4) void main_kernel(
    const float* __restrict__ x,
    const float* __restrict__ fg, const float* __restrict__ fb,
    const float* __restrict__ mg, const float* __restrict__ mb,
    const short* __restrict__ wbf, const float* __restrict__ cterm,
    float* __restrict__ out) {
  __shared__ __align__(16) char ubuf[3 * 16384];
  __shared__ float lp[32 * 100];
  __shared__ float mpr[32 * 20];
  __shared__ float redS[128], redQ[128], redV[128];
  __shared__ float meanA[32], rstdA[32], rnA[32], rn2A[32];
  __shared__ float mean2A[32], rstd2A[32];

  const int tid = threadIdx.x;
  const bool isProd = tid >= 256;
  const int rt = tid & 255;
  const int q = rt & 7, cgr = rt >> 3;  // px-quad, 8-channel group
  const int rw = rt >> 6;               // role-local wave 0..3
  const int lane = tid & 63;
  const int phalf = rw & 1, pxt = rw >> 1;  // consumer MFMA role
  const int lm = lane & 15, lk = lane >> 4;
  const int slotR =
      ((((lane >> 4) & 1) * 4 + (lane & 3)) * 8 + ((lane >> 2) & 3) * 2 + ((lane >> 5) & 1)) * 16;
  const int blkoff = ((q >> 2) * 8 + (cgr >> 2)) * 1024;
  const int sb = (q & 3) * 2 + ((cgr >> 1) & 1);

  // persistent accumulators
  float4v s4, q4, s2v;
  float4v aQ1[3], aQ2[3];
  s4[0] = s4[1] = s4[2] = s4[3] = 0.f;
  q4[0] = q4[1] = q4[2] = q4[3] = 0.f;
  s2v[0] = s2v[1] = s2v[2] = s2v[3] = 0.f;
#pragma unroll
  for (int i = 0; i < 3; i++) {
#pragma unroll
    for (int r = 0; r < 4; r++) {
      aQ1[i][r] = 0.f;
      aQ2[i][r] = 0.f;
    }
  }

#pragma unroll 1
  for (int ph = 0; ph < 2 * TILES_ + 2; ++ph) {
    const int sP = ph % 3;
    const int sC = (ph + 1) % 3;
    const bool pv = ph < 2 * TILES_;
    const int tp = ph >> 1, hp = ph & 1;
    const bool cv = ph >= 2;
    const int phc = ph - 2;
    const int tc = phc >> 1, hc2 = phc & 1;

    // ---- producer: load 8 float4 + pack -> ubuf[sP]; stats in registers ----
    if (isProd && pv) {
      const int n0 = (blockIdx.x * TILES_ + tp) * 32;
      const int bb = n0 >> 14, rem = n0 & 16383, hh = rem >> 7, w0 = rem & 127;
      const int c0 = hp * 256 + cgr * 8;
      const float* xp4 = x + (size_t)bb * C_ * HW_ + hh * 128 + w0 + q * 4;
      float4v xq[8];
#pragma unroll
      for (int j = 0; j < 8; j++) xq[j] = *(const float4v*)(xp4 + (size_t)(c0 + j) * HW_);
#pragma unroll
      for (int j = 0; j < 8; j++) {
        s4 += xq[j];
        q4 += xq[j] * xq[j];
      }
      char* buf = ubuf + sP * 16384;
#pragma unroll
      for (int r = 0; r < 4; r++) {
        int4v pk;
#pragma unroll
        for (int j2 = 0; j2 < 4; j2++) pk[j2] = pk2(xq[2 * j2][r], xq[2 * j2 + 1][r]);
        *(int4v*)(buf + blkoff + (((cgr & 1) * 4 + r) * 8 + sb) * 16) = pk;
      }
      if (hp == 1) {  // tile complete: publish stats partials, reset
#pragma unroll
        for (int o = 8; o < 64; o <<= 1) {
#pragma unroll
          for (int c = 0; c < 4; c++) {
            s4[c] += __shfl_down(s4[c], o);
            q4[c] += __shfl_down(q4[c], o);
          }
        }
        if (lane < 8) {
          *(float4v*)(redS + (rw * 8 + lane) * 4) = s4;
          *(float4v*)(redQ + (rw * 8 + lane) * 4) = q4;
        }
        s4[0] = s4[1] = s4[2] = s4[3] = 0.f;
        q4[0] = q4[1] = q4[2] = q4[3] = 0.f;
      }
    }
    // ---- consumer: finalize LN stats at start of each tile ----
    if (!isProd && cv && hc2 == 0 && tid < 32) {
      float ss = 0.f, qq = 0.f;
#pragma unroll
      for (int w = 0; w < 4; w++) {
        ss += redS[(w * 8 + (tid >> 2)) * 4 + (tid & 3)];
        qq += redQ[(w * 8 + (tid >> 2)) * 4 + (tid & 3)];
      }
      float mean = ss * (1.f / C_);
      float var = qq * (1.f / C_) - mean * mean;
      meanA[tid] = mean;
      rstdA[tid] = rsqrtf(var + 1e-5f);
    }
    __syncthreads();  // B1: stats ready; producer slot writes fenced later (B8)

    // ---- consumer: RMW x -> v in ubuf[sC] ----
    if (!isProd && cv) {
      char* buf = ubuf + sC * 16384;
      const int c0 = hc2 * 256 + cgr * 8;
      float fga[8], fba[8];
      *(float4v*)(fga) = *(const float4v*)(fg + c0);
      *(float4v*)(fga + 4) = *(const float4v*)(fg + c0 + 4);
      *(float4v*)(fba) = *(const float4v*)(fb + c0);
      *(float4v*)(fba + 4) = *(const float4v*)(fb + c0 + 4);
#pragma unroll
      for (int r = 0; r < 4; r++) {
        char* ad = buf + blkoff + (((cgr & 1) * 4 + r) * 8 + sb) * 16;
        short8 xc = *(short8*)ad;
        const int px = q * 4 + r;
        const float m = meanA[px], sd = rstdA[px];
        float vv[8];
#pragma unroll
        for (int j = 0; j < 8; j++) {
          float v = fmaf((bf2f(xc[j]) - m) * sd, fga[j], fba[j]);
          s2v[r] = fmaf(v, v, s2v[r]);
          vv[j] = v;
        }
        int4v pk;
#pragma unroll
        for (int j2 = 0; j2 < 4; j2++) pk[j2] = pk2(vv[2 * j2], vv[2 * j2 + 1]);
        *(int4v*)ad = pk;
      }
    }
    __syncthreads();  // B2: v ready for MFMA

    // ---- consumer: MFMA this half (acc across both halves) ----
    if (!isProd && cv) {
      char* buf = ubuf + sC * 16384;
#pragma unroll 2
      for (int ksl = 0; ksl < 8; ksl++) {
        const int ks = hc2 * 8 + ksl;
        short8 b0 = *(const short8*)(buf + (pxt * 8 + ksl) * 1024 + slotR);
        short8 b2 = sq8(b0);
#pragma unroll
        for (int i = 0; i < 3; i++) {
          const short* wr = wbf + (((phalf * 3 + i) * 16 + lm) << 10) + (lk << 3) + ks * 32;
          short8 aiv = *(const short8*)(wr);
          short8 amv = *(const short8*)(wr + 512);
          aQ1[i] = __builtin_amdgcn_mfma_f32_16x16x32_bf16(aiv, b2, aQ1[i], 0, 0, 0);
          aQ2[i] = __builtin_amdgcn_mfma_f32_16x16x32_bf16(amv, b0, aQ2[i], 0, 0, 0);
        }
      }
      if (hc2 == 1) {  // publish v^2 partials
#pragma unroll
        for (int o = 8; o < 64; o <<= 1) {
#pragma unroll
          for (int c = 0; c < 4; c++) s2v[c] += __shfl_down(s2v[c], o);
        }
        if (lane < 8) *(float4v*)(redV + (rw * 8 + lane) * 4) = s2v;
        s2v[0] = s2v[1] = s2v[2] = s2v[3] = 0.f;
      }
    }
    __syncthreads();  // B3

    // ---- epilogue phases (block-uniform condition) ----
    if (cv && hc2 == 1) {
      if (tid < 32) {
        float ss = 0.f;
#pragma unroll
        for (int w = 0; w < 4; w++) ss += redV[(w * 8 + (tid >> 2)) * 4 + (tid & 3)];
        float rn = 1.f / fmaxf(sqrtf(ss), 1e-12f);
        rnA[tid] = rn;
        rn2A[tid] = rn * rn;
      }
      __syncthreads();  // B4: rn ready
      if (!isProd) {
        const int pxx = pxt * 16 + lm;
        const float rn = rnA[pxx], rn2 = rn2A[pxx];
#pragma unroll
        for (int i = 0; i < 3; i++) {
#pragma unroll
          for (int r = 0; r < 4; r++) {
            const int p = (phalf * 3 + i) * 16 + lk * 4 + r;
            lp[pxx * 100 + p] =
                fmaf(-0.5f * rn2, aQ1[i][r], fmaf(rn, aQ2[i][r], cterm[p]));
            aQ1[i][r] = 0.f;
            aQ2[i][r] = 0.f;
          }
        }
      }
      __syncthreads();  // B5: lp ready
      for (int idx = tid; idx < 32 * K_; idx += 512) {
        const int pxx = idx / K_;
        const int k = idx - pxx * K_;
        const float* row = lp + pxx * 100 + k * M_;
        float mv = row[0];
#pragma unroll
        for (int m = 1; m < M_; m++) mv = fmaxf(mv, row[m]);
        mpr[pxx * 20 + k] = mv;
      }
      __syncthreads();  // B6
      if (tid < 32) {  // LN over K, two-pass (values ~ -470, var ~ 1e-3)
        float ss = 0.f;
        for (int k = 0; k < K_; k++) ss += mpr[tid * 20 + k];
        float m2 = ss * (1.f / K_);
        float qq = 0.f;
        for (int k = 0; k < K_; k++) {
          float d = mpr[tid * 20 + k] - m2;
          qq += d * d;
        }
        mean2A[tid] = m2;
        rstd2A[tid] = rsqrtf(qq * (1.f / K_) + 1e-5f);
      }
      __syncthreads();  // B7
      {
        const int n0c = (blockIdx.x * TILES_ + tc) * 32;
        const int bc = n0c >> 14, remc = n0c & 16383, hh2 = remc >> 7, w0c = remc & 127;
        float* obase = out + ((size_t)(bc * K_) * 128 + hh2) * 128 + w0c;
        for (int idx = tid; idx < 32 * K_; idx += 512) {
          const int k = idx >> 5, pxx = idx & 31;
          float v = fmaf((mpr[pxx * 20 + k] - mean2A[pxx]) * rstd2A[pxx], mg[k], mb[k]);
          obase[(size_t)k * HW_ + pxx] = v;
        }
      }
    }
    __syncthreads();  // B8: phase end (fences slot reuse + lp/red reuse)
  }
}

extern "C" void kernel_launch(void* const* d_in, const int* in_sizes, int n_in,
                              void* d_out, int out_size, void* d_ws, size_t ws_size,
                              hipStream_t stream) {
  const float* x = (const float*)d_in[0];
  const float* means = (const float*)d_in[1];
  const float* diag = (const float*)d_in[2];
  const float* fg = (const float*)d_in[3];
  const float* fb = (const float*)d_in[4];
  const float* mg = (const float*)d_in[5];
  const float* mb = (const float*)d_in[6];
  float* out = (float*)d_out;

  short* wbf = (short*)d_ws;                                     // 96*1024*2 B
  float* cterm = (float*)((char*)d_ws + (size_t)P2 * 1024 * 2);  // +96*4 B

  prep_kernel<<<P2, 256, 0, stream>>>(means, diag, wbf, cterm);
  main_kernel<<<GRID_, 512, 0, stream>>>(x, fg, fb, mg, mb, wbf, cterm, out);
}